// Round 1
// baseline (384.430 us; speedup 1.0000x reference)
//
#include <hip/hip_runtime.h>
#include <stdint.h>

// GraphVertModel: B=32, M=512, F_N=64, D=128, GS=4, L=8
// Strategy (round 1): bf16-MFMA everywhere, fp32 accumulation & fp32 residual
// stream. m97-style 2-phase double-buffered LDS GEMM (global_load_lds w=16).
// ws layout (needs ~133 MB):
//   Gh   bf16 [B][GS][M][M]       64 MB  @ 0
//   MhT  bf16 [B][GS][D][M]       16 MB  @ 64M   (multi stored transposed)
//   xo   f32  [B][GS][M][D]       32 MB  @ 80M   (relu'd adjacency output)
//   h    f32  [B][M][D]            8 MB  @ 112M
//   hb   bf16 [B][M][D]            4 MB  @ 120M
//   xb   bf16 [B][M][FN]           2 MB  @ 124M
//   W0bT bf16 [GS][D][FN]         64 KB  @ 126M
//   WlbT bf16 [7][GS][D][D]      896 KB  @ 126M+64K

#define B_  32
#define M_  512
#define FN_ 64
#define D_  128
#define GS_ 4
#define L_  8

typedef __attribute__((ext_vector_type(8))) short short8;
typedef __attribute__((ext_vector_type(4))) float f32x4;

__device__ __forceinline__ unsigned short f2bf(float f) {
  union { float f; unsigned int u; } v; v.f = f;
  return (unsigned short)((v.u + 0x7FFFu + ((v.u >> 16) & 1u)) >> 16);  // RTNE
}

__device__ __forceinline__ void gl16(const void* g, void* l) {
  __builtin_amdgcn_global_load_lds((const __attribute__((address_space(1))) void*)g,
                                   (__attribute__((address_space(3))) void*)l, 16, 0, 0);
}

// ---- fp32 -> bf16 vectorized convert -------------------------------------
__global__ void k_conv(const float4* __restrict__ src, ushort4* __restrict__ dst, int n4) {
  int i = blockIdx.x * blockDim.x + threadIdx.x;
  int st = gridDim.x * blockDim.x;
  for (; i < n4; i += st) {
    float4 v = src[i];
    ushort4 o;
    o.x = f2bf(v.x); o.y = f2bf(v.y); o.z = f2bf(v.z); o.w = f2bf(v.w);
    dst[i] = o;
  }
}

// ---- weights: convert + transpose ([g][c][p] -> [g][p][c]) ----------------
__global__ void k_convW(const float* __restrict__ W0, const float* __restrict__ Wl,
                        unsigned short* __restrict__ W0bT, unsigned short* __restrict__ WlbT) {
  int i = blockIdx.x * blockDim.x + threadIdx.x;
  const int n0 = GS_ * FN_ * D_;
  if (i < n0) {
    int g = i / (FN_ * D_), r = i % (FN_ * D_), c = r / D_, p = r % D_;
    W0bT[((size_t)g * D_ + p) * FN_ + c] = f2bf(W0[i]);
  } else {
    int j = i - n0;
    if (j < 7 * GS_ * D_ * D_) {
      int l = j / (GS_ * D_ * D_), r = j % (GS_ * D_ * D_);
      int g = r / (D_ * D_), r2 = r % (D_ * D_), c = r2 / D_, p = r2 % D_;
      WlbT[(((size_t)l * GS_ + g) * D_ + p) * D_ + c] = f2bf(Wl[j]);
    }
  }
}

// ---- tiled bf16 MFMA GEMM, 128x128 block tile, BK=32, 4 waves (2x2 of 64x64)
// grid = B*GS*4 (mt fastest).  A: [128 rows][K] row-major (row stride aRS halfs),
// B-source: [128 "cols"][K] row-major (k-contiguous; this is why MhT/WbT are
// stored transposed).  EPI 0: +bias, store bf16 transposed [p][n] (-> MhT).
// EPI 1: relu, store f32 [m][p] (-> xo).
template<int NK, int EPI>
__launch_bounds__(256)
__global__ void k_gemm(const unsigned short* __restrict__ A0,
                       const unsigned short* __restrict__ B0,
                       int aRS, int bRS,
                       int aSB, int aSG, int bSB, int bSG,
                       unsigned short* __restrict__ outBf,
                       float* __restrict__ outF,
                       const float* __restrict__ bias) {
  __shared__ __align__(16) unsigned short sm[2][2][4096];  // [buf][A/B] 8KB each
  const int t = threadIdx.x;
  const int bid = blockIdx.x;
  const int mt = bid & 3, g = (bid >> 2) & 3, b = bid >> 4;
  const unsigned short* Ap = A0 + (size_t)b * aSB + (size_t)g * aSG + (size_t)mt * 128 * aRS;
  const unsigned short* Bp = B0 + (size_t)b * bSB + (size_t)g * bSG;

  const int tr = t >> 2;         // staging row 0..63
  const int tc = (t & 3) * 8;    // halfs within row (16B granule)

  // prologue: stage k-step 0 into buffer 0
  {
    const unsigned short* ga = Ap + (size_t)tr * aRS + tc;
    const unsigned short* gb = Bp + (size_t)tr * bRS + tc;
    gl16(ga, &sm[0][0][t * 8]);
    gl16(ga + (size_t)64 * aRS, &sm[0][0][2048 + t * 8]);
    gl16(gb, &sm[0][1][t * 8]);
    gl16(gb + (size_t)64 * bRS, &sm[0][1][2048 + t * 8]);
  }

  const int lane = t & 63;
  const int wm = ((t >> 7) & 1) * 64;
  const int wp = ((t >> 6) & 1) * 64;
  const int lr = lane & 15;
  const int lk = (lane >> 4) * 8;

  f32x4 acc[4][4];
#pragma unroll
  for (int i = 0; i < 4; ++i)
#pragma unroll
    for (int j = 0; j < 4; ++j) acc[i][j] = (f32x4){0.f, 0.f, 0.f, 0.f};

  int cur = 0;
  for (int ks = 0; ks < NK; ++ks) {
    __syncthreads();  // drains vmcnt -> staged buf[cur] visible; prev reads done
    if (ks + 1 < NK) {
      const int nb = cur ^ 1;
      const unsigned short* ga = Ap + (size_t)(ks + 1) * 32 + (size_t)tr * aRS + tc;
      const unsigned short* gb = Bp + (size_t)(ks + 1) * 32 + (size_t)tr * bRS + tc;
      gl16(ga, &sm[nb][0][t * 8]);
      gl16(ga + (size_t)64 * aRS, &sm[nb][0][2048 + t * 8]);
      gl16(gb, &sm[nb][1][t * 8]);
      gl16(gb + (size_t)64 * bRS, &sm[nb][1][2048 + t * 8]);
    }
    const unsigned short* sa = sm[cur][0];
    const unsigned short* sb = sm[cur][1];
    short8 af[4], bfr[4];
#pragma unroll
    for (int i = 0; i < 4; ++i)
      af[i] = *(const short8*)&sa[(wm + i * 16 + lr) * 32 + lk];
#pragma unroll
    for (int j = 0; j < 4; ++j)
      bfr[j] = *(const short8*)&sb[(wp + j * 16 + lr) * 32 + lk];
#pragma unroll
    for (int i = 0; i < 4; ++i)
#pragma unroll
      for (int j = 0; j < 4; ++j)
        acc[i][j] = __builtin_amdgcn_mfma_f32_16x16x32_bf16(af[i], bfr[j], acc[i][j], 0, 0, 0);
    cur ^= 1;
  }

  const int rb = (lane >> 4) * 4;  // C/D: col = lane&15, row = (lane>>4)*4 + idx
  if constexpr (EPI == 0) {
#pragma unroll
    for (int j = 0; j < 4; ++j) {
      const int p = wp + j * 16 + lr;
      const float bv = bias[g * D_ + p];
      unsigned short* op = outBf + ((size_t)(b * GS_ + g) * D_ + p) * M_;
#pragma unroll
      for (int i = 0; i < 4; ++i) {
        const int n = mt * 128 + wm + i * 16 + rb;
        f32x4 v = acc[i][j];
        ushort4 o;
        o.x = f2bf(v[0] + bv); o.y = f2bf(v[1] + bv);
        o.z = f2bf(v[2] + bv); o.w = f2bf(v[3] + bv);
        *(ushort4*)(op + n) = o;  // transposed store: [p][n], n contiguous
      }
    }
  } else {
#pragma unroll
    for (int i = 0; i < 4; ++i) {
      const int m = mt * 128 + wm + i * 16 + rb;
      float* op = outF + ((size_t)(b * GS_ + g) * M_ + m) * D_;
#pragma unroll
      for (int j = 0; j < 4; ++j) {
        const int p = wp + j * 16 + lr;
        f32x4 v = acc[i][j];
        op[p]          = fmaxf(v[0], 0.f);
        op[p + D_]     = fmaxf(v[1], 0.f);
        op[p + 2 * D_] = fmaxf(v[2], 0.f);
        op[p + 3 * D_] = fmaxf(v[3], 0.f);
      }
    }
  }
}

// ---- max over channels + residual; also emits bf16 copy of h --------------
template<int FIRST>
__global__ void k_maxres(const float4* __restrict__ xo, float4* __restrict__ h,
                         ushort4* __restrict__ hb) {
  const int PL = M_ * D_ / 4;  // float4s per (b,g) plane
  int i = blockIdx.x * 256 + threadIdx.x;  // exactly B_*PL threads
  int b = i / PL, r = i % PL;
  const float4* xp = xo + (size_t)b * GS_ * PL + r;
  float4 v = xp[0];
#pragma unroll
  for (int g = 1; g < GS_; ++g) {
    float4 u = xp[(size_t)g * PL];
    v.x = fmaxf(v.x, u.x); v.y = fmaxf(v.y, u.y);
    v.z = fmaxf(v.z, u.z); v.w = fmaxf(v.w, u.w);
  }
  if (!FIRST) {
    float4 hv = h[i];
    v.x += hv.x; v.y += hv.y; v.z += hv.z; v.w += hv.w;
  }
  h[i] = v;
  ushort4 o; o.x = f2bf(v.x); o.y = f2bf(v.y); o.z = f2bf(v.z); o.w = f2bf(v.w);
  hb[i] = o;
}

// ---- final projection: out[b,m] = h[b,m,:] . Wout + bout ------------------
__global__ void k_out(const float* __restrict__ h, const float* __restrict__ Wout,
                      const float* __restrict__ bout, float* __restrict__ out) {
  const int w = blockIdx.x * 4 + (threadIdx.x >> 6);  // row id over B*M
  const int lane = threadIdx.x & 63;
  const float2 hv = ((const float2*)(h + (size_t)w * D_))[lane];
  const float2 wv = ((const float2*)Wout)[lane];
  float s = hv.x * wv.x + hv.y * wv.y;
#pragma unroll
  for (int o = 32; o; o >>= 1) s += __shfl_down(s, o);
  if (lane == 0) out[w] = s + bout[0];
}

extern "C" void kernel_launch(void* const* d_in, const int* in_sizes, int n_in,
                              void* d_out, int out_size, void* d_ws, size_t ws_size,
                              hipStream_t stream) {
  const float* G    = (const float*)d_in[0];
  const float* x    = (const float*)d_in[1];
  const float* W0   = (const float*)d_in[2];
  const float* b0   = (const float*)d_in[3];
  const float* Wl   = (const float*)d_in[4];
  const float* bl   = (const float*)d_in[5];
  const float* Wout = (const float*)d_in[6];
  const float* bout = (const float*)d_in[7];

  char* ws = (char*)d_ws;
  unsigned short* Gh   = (unsigned short*)(ws);
  unsigned short* MhT  = (unsigned short*)(ws + 67108864);
  float*          xo   = (float*)(ws + 83886080);
  float*          h    = (float*)(ws + 117440512);
  unsigned short* hb   = (unsigned short*)(ws + 125829120);
  unsigned short* xb   = (unsigned short*)(ws + 130023424);
  unsigned short* W0bT = (unsigned short*)(ws + 132120576);
  unsigned short* WlbT = (unsigned short*)(ws + 132186112);

  k_conv<<<2048, 256, 0, stream>>>((const float4*)G, (ushort4*)Gh, (B_ * GS_ * M_ * M_) / 4);
  k_conv<<<1024, 256, 0, stream>>>((const float4*)x, (ushort4*)xb, (B_ * M_ * FN_) / 4);
  k_convW<<<1920, 256, 0, stream>>>(W0, Wl, W0bT, WlbT);

  // layer 0 (C = FN = 64, no residual)
  k_gemm<FN_ / 32, 0><<<512, 256, 0, stream>>>(xb, W0bT, FN_, FN_,
      M_ * FN_, 0, 0, D_ * FN_, MhT, nullptr, b0);
  k_gemm<M_ / 32, 1><<<512, 256, 0, stream>>>(Gh, MhT, M_, M_,
      GS_ * M_ * M_, M_ * M_, GS_ * D_ * M_, D_ * M_, nullptr, xo, nullptr);
  k_maxres<1><<<2048, 256, 0, stream>>>((const float4*)xo, (float4*)h, (ushort4*)hb);

  // layers 1..7 (C = D = 128, residual)
  for (int l = 1; l < L_; ++l) {
    k_gemm<D_ / 32, 0><<<512, 256, 0, stream>>>(hb, WlbT + (size_t)(l - 1) * GS_ * D_ * D_,
        D_, D_, M_ * D_, 0, 0, D_ * D_, MhT, nullptr, bl + (size_t)(l - 1) * GS_ * D_);
    k_gemm<M_ / 32, 1><<<512, 256, 0, stream>>>(Gh, MhT, M_, M_,
        GS_ * M_ * M_, M_ * M_, GS_ * D_ * M_, D_ * M_, nullptr, xo, nullptr);
    k_maxres<0><<<2048, 256, 0, stream>>>((const float4*)xo, (float4*)h, (ushort4*)hb);
  }

  k_out<<<4096, 256, 0, stream>>>(h, Wout, bout, (float*)d_out);
}

// Round 2
// 317.695 us; speedup vs baseline: 1.2101x; 1.2101x over previous
//
#include <hip/hip_runtime.h>
#include <stdint.h>

// GraphVertModel: B=32, M=512, F_N=64, D=128, GS=4, L=8
// Round 2: fuse adjacency-GEMM + relu + channel-max + residual into one
// kernel (k_fused) with wave-private double-buffered LDS pipelines
// (no per-K-step barriers, counted vmcnt(8)), eliminating the xo
// intermediate (64 MB/layer) and the k_maxres pass.
// ws layout (~100 MB):
//   Gh   bf16 [B][GS][M][M]   64 MB @ 0
//   MhT  bf16 [B][GS][D][M]   16 MB @ 64M    (multi, transposed [p][n])
//   h    f32  [B][M][D]        8 MB @ 80M
//   hb   bf16 [B][M][D]        4 MB @ 88M
//   xb   bf16 [B][M][FN]       2 MB @ 92M
//   W0bT bf16 [GS][D][FN]     64 KB @ 94M
//   WlbT bf16 [7][GS][D][D]  896 KB @ 94M+64K

#define B_  32
#define M_  512
#define FN_ 64
#define D_  128
#define GS_ 4
#define L_  8

typedef __attribute__((ext_vector_type(8))) short short8;
typedef __attribute__((ext_vector_type(4))) float f32x4;
typedef unsigned short us;

__device__ __forceinline__ us f2bf(float f) {
  union { float f; unsigned int u; } v; v.f = f;
  return (us)((v.u + 0x7FFFu + ((v.u >> 16) & 1u)) >> 16);  // RTNE
}

__device__ __forceinline__ void gl16(const void* g, void* l) {
  __builtin_amdgcn_global_load_lds((const __attribute__((address_space(1))) void*)g,
                                   (__attribute__((address_space(3))) void*)l, 16, 0, 0);
}

// ---- fp32 -> bf16 vectorized convert -------------------------------------
__global__ void k_conv(const float4* __restrict__ src, ushort4* __restrict__ dst, int n4) {
  int i = blockIdx.x * blockDim.x + threadIdx.x;
  int st = gridDim.x * blockDim.x;
  for (; i < n4; i += st) {
    float4 v = src[i];
    ushort4 o;
    o.x = f2bf(v.x); o.y = f2bf(v.y); o.z = f2bf(v.z); o.w = f2bf(v.w);
    dst[i] = o;
  }
}

// ---- weights: convert + transpose ([g][c][p] -> [g][p][c]) ----------------
__global__ void k_convW(const float* __restrict__ W0, const float* __restrict__ Wl,
                        us* __restrict__ W0bT, us* __restrict__ WlbT) {
  int i = blockIdx.x * blockDim.x + threadIdx.x;
  const int n0 = GS_ * FN_ * D_;
  if (i < n0) {
    int g = i / (FN_ * D_), r = i % (FN_ * D_), c = r / D_, p = r % D_;
    W0bT[((size_t)g * D_ + p) * FN_ + c] = f2bf(W0[i]);
  } else {
    int j = i - n0;
    if (j < 7 * GS_ * D_ * D_) {
      int l = j / (GS_ * D_ * D_), r = j % (GS_ * D_ * D_);
      int g = r / (D_ * D_), r2 = r % (D_ * D_), c = r2 / D_, p = r2 % D_;
      WlbT[(((size_t)l * GS_ + g) * D_ + p) * D_ + c] = f2bf(Wl[j]);
    }
  }
}

// ---- per-channel linear GEMM (multi = h@W + b), output transposed [p][n] --
// 128x128 tile, BK=32, 4 waves (2x2 of 64x64). A: [512][aRS] row-major.
// B: [g][D][aRS] (k-contiguous, pre-transposed weights).
template<int NK>
__launch_bounds__(256)
__global__ void k_lin(const us* __restrict__ A0, const us* __restrict__ B0,
                      int aRS, int aSB, int bSG,
                      us* __restrict__ outBf, const float* __restrict__ bias) {
  __shared__ __align__(16) us sm[2][2][4096];
  const int t = threadIdx.x;
  const int bid = blockIdx.x;
  const int mt = bid & 3, g = (bid >> 2) & 3, b = bid >> 4;
  const us* Ap = A0 + (size_t)b * aSB + (size_t)mt * 128 * aRS;
  const us* Bp = B0 + (size_t)g * bSG;

  const int tr = t >> 2;
  const int tc = (t & 3) * 8;

  {
    const us* ga = Ap + (size_t)tr * aRS + tc;
    const us* gb = Bp + (size_t)tr * aRS + tc;
    gl16(ga, &sm[0][0][t * 8]);
    gl16(ga + (size_t)64 * aRS, &sm[0][0][2048 + t * 8]);
    gl16(gb, &sm[0][1][t * 8]);
    gl16(gb + (size_t)64 * aRS, &sm[0][1][2048 + t * 8]);
  }

  const int lane = t & 63;
  const int wm = ((t >> 7) & 1) * 64;
  const int wp = ((t >> 6) & 1) * 64;
  const int lr = lane & 15;
  const int lk = (lane >> 4) * 8;

  f32x4 acc[4][4];
#pragma unroll
  for (int i = 0; i < 4; ++i)
#pragma unroll
    for (int j = 0; j < 4; ++j) acc[i][j] = (f32x4){0.f, 0.f, 0.f, 0.f};

  int cur = 0;
  for (int ks = 0; ks < NK; ++ks) {
    __syncthreads();
    if (ks + 1 < NK) {
      const int nb = cur ^ 1;
      const us* ga = Ap + (size_t)(ks + 1) * 32 + (size_t)tr * aRS + tc;
      const us* gb = Bp + (size_t)(ks + 1) * 32 + (size_t)tr * aRS + tc;
      gl16(ga, &sm[nb][0][t * 8]);
      gl16(ga + (size_t)64 * aRS, &sm[nb][0][2048 + t * 8]);
      gl16(gb, &sm[nb][1][t * 8]);
      gl16(gb + (size_t)64 * aRS, &sm[nb][1][2048 + t * 8]);
    }
    const us* sa = sm[cur][0];
    const us* sb = sm[cur][1];
    short8 af[4], bfr[4];
#pragma unroll
    for (int i = 0; i < 4; ++i)
      af[i] = *(const short8*)&sa[(wm + i * 16 + lr) * 32 + lk];
#pragma unroll
    for (int j = 0; j < 4; ++j)
      bfr[j] = *(const short8*)&sb[(wp + j * 16 + lr) * 32 + lk];
#pragma unroll
    for (int i = 0; i < 4; ++i)
#pragma unroll
      for (int j = 0; j < 4; ++j)
        acc[i][j] = __builtin_amdgcn_mfma_f32_16x16x32_bf16(af[i], bfr[j], acc[i][j], 0, 0, 0);
    cur ^= 1;
  }

  const int rb = (lane >> 4) * 4;
#pragma unroll
  for (int j = 0; j < 4; ++j) {
    const int p = wp + j * 16 + lr;
    const float bv = bias[g * D_ + p];
    us* op = outBf + ((size_t)(b * GS_ + g) * D_ + p) * M_;
#pragma unroll
    for (int i = 0; i < 4; ++i) {
      const int n = mt * 128 + wm + i * 16 + rb;
      f32x4 v = acc[i][j];
      ushort4 o;
      o.x = f2bf(v[0] + bv); o.y = f2bf(v[1] + bv);
      o.z = f2bf(v[2] + bv); o.w = f2bf(v[3] + bv);
      *(ushort4*)(op + n) = o;
    }
  }
}

// ---- fused adjacency GEMM + relu + channel-max + residual -----------------
// grid 256 (b,mt64 tiles, XCD-swizzled), 512 thr = 8 waves = 4 groups x 2.
// Group g: channel g, 64 rows x 128 cols; wave: 64x64 (4x4 acc).
// Wave-private double-buffered LDS (16KB/wave): A-tile duplicated per wave,
// B-half disjoint -> no barriers in K-loop; counted s_waitcnt vmcnt(8).
// Epilogue: per-group relu'd f32 tiles in LDS (4x32KB, reusing the staging
// space), cross-group max, +residual, store h (f32) and hb (bf16).
template<int FIRST>
__launch_bounds__(512, 2)
__global__ void k_fused(const us* __restrict__ Gh, const us* __restrict__ MhT,
                        float* __restrict__ h, us* __restrict__ hb) {
  __shared__ __align__(16) us sm[65536];  // 128 KB
  const int bid = blockIdx.x;
  const int swz = (bid & 7) * 32 + (bid >> 3);   // bijective, 8 XCD chunks
  const int b = swz >> 3, mt = swz & 7;

  const int t = threadIdx.x;
  const int w = t >> 6;          // wave 0..7
  const int g = w >> 1;          // channel 0..3
  const int wp = (w & 1) * 64;   // col half within 128
  const int lane = t & 63;
  const int lr = lane & 15;
  const int kq = lane >> 4;

  const us* AgB = Gh + ((size_t)(b * GS_ + g) * M_ + mt * 64) * M_;
  const us* BgB = MhT + ((size_t)(b * GS_ + g) * D_ + wp) * M_;
  const int aoff = (lane >> 2) * M_ + (lane & 3) * 8;
  us* smW = sm + w * 8192;       // wave's 16KB (half-units)

#define STG(c, ks) do { \
    const us* ga_ = AgB + (ks) * 32 + aoff; \
    const us* gb_ = BgB + (ks) * 32 + aoff; \
    us* ld_ = smW + (c) * 4096 + lane * 8; \
    gl16(ga_,              ld_); \
    gl16(ga_ + 16 * M_,    ld_ + 512); \
    gl16(ga_ + 32 * M_,    ld_ + 1024); \
    gl16(ga_ + 48 * M_,    ld_ + 1536); \
    gl16(gb_,              ld_ + 2048); \
    gl16(gb_ + 16 * M_,    ld_ + 2560); \
    gl16(gb_ + 32 * M_,    ld_ + 3072); \
    gl16(gb_ + 48 * M_,    ld_ + 3584); \
  } while (0)

  f32x4 acc[4][4];
#pragma unroll
  for (int i = 0; i < 4; ++i)
#pragma unroll
    for (int j = 0; j < 4; ++j) acc[i][j] = (f32x4){0.f, 0.f, 0.f, 0.f};

  STG(0, 0);

  const int fo = lr * 32 + kq * 8;
#pragma unroll 2
  for (int ks = 0; ks < 16; ++ks) {
    const int cur = ks & 1;
    // prior ds_reads of buffer cur^1 are long complete (their MFMAs issued),
    // cheap fence before overwriting it:
    asm volatile("s_waitcnt lgkmcnt(0)" ::: "memory");
    if (ks < 15) {
      STG(cur ^ 1, ks + 1);
      asm volatile("s_waitcnt vmcnt(8)" ::: "memory");   // cur buffer landed
    } else {
      asm volatile("s_waitcnt vmcnt(0)" ::: "memory");
    }
    const us* sa = smW + cur * 4096;
    const us* sb = sa + 2048;
    short8 af[4], bf[4];
#pragma unroll
    for (int i = 0; i < 4; ++i) af[i] = *(const short8*)&sa[i * 512 + fo];
#pragma unroll
    for (int j = 0; j < 4; ++j) bf[j] = *(const short8*)&sb[j * 512 + fo];
#pragma unroll
    for (int i = 0; i < 4; ++i)
#pragma unroll
      for (int j = 0; j < 4; ++j)
        acc[i][j] = __builtin_amdgcn_mfma_f32_16x16x32_bf16(af[i], bf[j], acc[i][j], 0, 0, 0);
  }
#undef STG

  __syncthreads();  // all waves done with staging buffers; reuse LDS as f32

  {  // write my group's relu'd tile: region g, [64][128] f32
    float* red = (float*)sm + (size_t)g * 8192;
    const int rb = kq * 4;
#pragma unroll
    for (int i = 0; i < 4; ++i)
#pragma unroll
      for (int j = 0; j < 4; ++j) {
        float* cp = red + (size_t)(i * 16 + rb) * D_ + wp + j * 16 + lr;
        cp[0]      = fmaxf(acc[i][j][0], 0.f);
        cp[D_]     = fmaxf(acc[i][j][1], 0.f);
        cp[2 * D_] = fmaxf(acc[i][j][2], 0.f);
        cp[3 * D_] = fmaxf(acc[i][j][3], 0.f);
      }
  }
  __syncthreads();

  {  // cross-group max + residual + store (each thread: 16 elems)
    const int m_l = t >> 3, p0 = (t & 7) * 16;
    const float* r0 = (float*)sm + (size_t)m_l * D_ + p0;
    float4 vm[4];
#pragma unroll
    for (int k = 0; k < 4; ++k) vm[k] = ((const float4*)r0)[k];
#pragma unroll
    for (int gg = 1; gg < 4; ++gg) {
      const float4* rg = (const float4*)(r0 + (size_t)gg * 8192);
#pragma unroll
      for (int k = 0; k < 4; ++k) {
        float4 u = rg[k];
        vm[k].x = fmaxf(vm[k].x, u.x); vm[k].y = fmaxf(vm[k].y, u.y);
        vm[k].z = fmaxf(vm[k].z, u.z); vm[k].w = fmaxf(vm[k].w, u.w);
      }
    }
    const size_t ho = ((size_t)b * M_ + mt * 64 + m_l) * D_ + p0;
    float4* hp = (float4*)(h + ho);
    ushort4* hbp = (ushort4*)(hb + ho);
#pragma unroll
    for (int k = 0; k < 4; ++k) {
      float4 v = vm[k];
      if (!FIRST) {
        float4 hv = hp[k];
        v.x += hv.x; v.y += hv.y; v.z += hv.z; v.w += hv.w;
      }
      hp[k] = v;
      ushort4 o;
      o.x = f2bf(v.x); o.y = f2bf(v.y); o.z = f2bf(v.z); o.w = f2bf(v.w);
      hp[k] = v;
      hbp[k] = o;
    }
  }
}

// ---- final projection: out[b,m] = h[b,m,:] . Wout + bout ------------------
__global__ void k_out(const float* __restrict__ h, const float* __restrict__ Wout,
                      const float* __restrict__ bout, float* __restrict__ out) {
  const int w = blockIdx.x * 4 + (threadIdx.x >> 6);
  const int lane = threadIdx.x & 63;
  const float2 hv = ((const float2*)(h + (size_t)w * D_))[lane];
  const float2 wv = ((const float2*)Wout)[lane];
  float s = hv.x * wv.x + hv.y * wv.y;
#pragma unroll
  for (int o = 32; o; o >>= 1) s += __shfl_down(s, o);
  if (lane == 0) out[w] = s + bout[0];
}

extern "C" void kernel_launch(void* const* d_in, const int* in_sizes, int n_in,
                              void* d_out, int out_size, void* d_ws, size_t ws_size,
                              hipStream_t stream) {
  const float* G    = (const float*)d_in[0];
  const float* x    = (const float*)d_in[1];
  const float* W0   = (const float*)d_in[2];
  const float* b0   = (const float*)d_in[3];
  const float* Wl   = (const float*)d_in[4];
  const float* bl   = (const float*)d_in[5];
  const float* Wout = (const float*)d_in[6];
  const float* bout = (const float*)d_in[7];

  char* ws = (char*)d_ws;
  us*    Gh   = (us*)(ws);
  us*    MhT  = (us*)(ws + 67108864);
  float* h    = (float*)(ws + 83886080);
  us*    hb   = (us*)(ws + 92274688);
  us*    xb   = (us*)(ws + 96468992);
  us*    W0bT = (us*)(ws + 98566144);
  us*    WlbT = (us*)(ws + 98631680);

  k_conv<<<2048, 256, 0, stream>>>((const float4*)G, (ushort4*)Gh, (B_ * GS_ * M_ * M_) / 4);
  k_conv<<<1024, 256, 0, stream>>>((const float4*)x, (ushort4*)xb, (B_ * M_ * FN_) / 4);
  k_convW<<<1920, 256, 0, stream>>>(W0, Wl, W0bT, WlbT);

  // layer 0
  k_lin<FN_ / 32><<<512, 256, 0, stream>>>(xb, W0bT, FN_, M_ * FN_, D_ * FN_, MhT, b0);
  k_fused<1><<<256, 512, 0, stream>>>(Gh, MhT, h, hb);

  // layers 1..7
  for (int l = 1; l < L_; ++l) {
    k_lin<D_ / 32><<<512, 256, 0, stream>>>(hb, WlbT + (size_t)(l - 1) * GS_ * D_ * D_,
        D_, M_ * D_, D_ * D_, MhT, bl + (size_t)(l - 1) * GS_ * D_);
    k_fused<0><<<256, 512, 0, stream>>>(Gh, MhT, h, hb);
  }

  k_out<<<4096, 256, 0, stream>>>(h, Wout, bout, (float*)d_out);
}

// Round 3
// 314.349 us; speedup vs baseline: 1.2229x; 1.0106x over previous
//
#include <hip/hip_runtime.h>
#include <stdint.h>

// GraphVertModel: B=32, M=512, F_N=64, D=128, GS=4, L=8
// Round 3: (1) conflict-free XOR-swizzled LDS (pre-swizzled global source for
// global_load_lds + swizzled ds_read addr), (2) k_fused v2: 3-buffer
// block-cooperative staging, 1 raw s_barrier/K-step, counted vmcnt(6),
// (3) final-layer epilogue computes the Wout projection (k_out folded).
// ws layout (~100 MB): Gh 64M @0 | MhT 16M @64M | h 8M @80M | hb 4M @88M |
//                      xb 2M @92M | W0bT @94M | WlbT @94M+64K

#define B_  32
#define M_  512
#define FN_ 64
#define D_  128
#define GS_ 4
#define L_  8

typedef __attribute__((ext_vector_type(8))) short short8;
typedef __attribute__((ext_vector_type(4))) float f32x4;
typedef unsigned short us;

__device__ __forceinline__ us f2bf(float f) {
  union { float f; unsigned int u; } v; v.f = f;
  return (us)((v.u + 0x7FFFu + ((v.u >> 16) & 1u)) >> 16);  // RTNE
}

__device__ __forceinline__ void gl16(const void* g, void* l) {
  __builtin_amdgcn_global_load_lds((const __attribute__((address_space(1))) void*)g,
                                   (__attribute__((address_space(3))) void*)l, 16, 0, 0);
}

// ---- fp32 -> bf16 vectorized convert -------------------------------------
__global__ void k_conv(const float4* __restrict__ src, ushort4* __restrict__ dst, int n4) {
  int i = blockIdx.x * blockDim.x + threadIdx.x;
  int st = gridDim.x * blockDim.x;
  for (; i < n4; i += st) {
    float4 v = src[i];
    ushort4 o;
    o.x = f2bf(v.x); o.y = f2bf(v.y); o.z = f2bf(v.z); o.w = f2bf(v.w);
    dst[i] = o;
  }
}

// ---- weights: convert + transpose ([g][c][p] -> [g][p][c]) ----------------
__global__ void k_convW(const float* __restrict__ W0, const float* __restrict__ Wl,
                        us* __restrict__ W0bT, us* __restrict__ WlbT) {
  int i = blockIdx.x * blockDim.x + threadIdx.x;
  const int n0 = GS_ * FN_ * D_;
  if (i < n0) {
    int g = i / (FN_ * D_), r = i % (FN_ * D_), c = r / D_, p = r % D_;
    W0bT[((size_t)g * D_ + p) * FN_ + c] = f2bf(W0[i]);
  } else {
    int j = i - n0;
    if (j < 7 * GS_ * D_ * D_) {
      int l = j / (GS_ * D_ * D_), r = j % (GS_ * D_ * D_);
      int g = r / (D_ * D_), r2 = r % (D_ * D_), c = r2 / D_, p = r2 % D_;
      WlbT[(((size_t)l * GS_ + g) * D_ + p) * D_ + c] = f2bf(Wl[j]);
    }
  }
}

// ---- per-channel linear GEMM (multi = h@W + b), output transposed [p][n] --
// 128x128 tile, BK=32, 4 waves (2x2 of 64x64). Swizzled LDS (chunk ^= (row>>1)&3).
template<int NK>
__launch_bounds__(256)
__global__ void k_lin(const us* __restrict__ A0, const us* __restrict__ B0,
                      int aRS, int aSB, int bSG,
                      us* __restrict__ outBf, const float* __restrict__ bias) {
  __shared__ __align__(16) us sm[2][2][4096];
  const int t = threadIdx.x;
  const int bid = blockIdx.x;
  const int mt = bid & 3, g = (bid >> 2) & 3, b = bid >> 4;
  const us* Ap = A0 + (size_t)b * aSB + (size_t)mt * 128 * aRS;
  const us* Bp = B0 + (size_t)g * bSG;

  const int tr = t >> 2;
  const int tcs = ((t & 3) ^ ((t >> 3) & 3)) * 8;   // pre-swizzled source chunk

  {
    const us* ga = Ap + (size_t)tr * aRS + tcs;
    const us* gb = Bp + (size_t)tr * aRS + tcs;
    gl16(ga, &sm[0][0][t * 8]);
    gl16(ga + (size_t)64 * aRS, &sm[0][0][2048 + t * 8]);
    gl16(gb, &sm[0][1][t * 8]);
    gl16(gb + (size_t)64 * aRS, &sm[0][1][2048 + t * 8]);
  }

  const int lane = t & 63;
  const int wm = ((t >> 7) & 1) * 64;
  const int wp = ((t >> 6) & 1) * 64;
  const int lr = lane & 15;
  const int kk = (((lane >> 4) ^ ((lane >> 1) & 3))) * 8;  // swizzled read chunk

  f32x4 acc[4][4];
#pragma unroll
  for (int i = 0; i < 4; ++i)
#pragma unroll
    for (int j = 0; j < 4; ++j) acc[i][j] = (f32x4){0.f, 0.f, 0.f, 0.f};

  int cur = 0;
  for (int ks = 0; ks < NK; ++ks) {
    __syncthreads();
    if (ks + 1 < NK) {
      const int nb = cur ^ 1;
      const us* ga = Ap + (size_t)(ks + 1) * 32 + (size_t)tr * aRS + tcs;
      const us* gb = Bp + (size_t)(ks + 1) * 32 + (size_t)tr * aRS + tcs;
      gl16(ga, &sm[nb][0][t * 8]);
      gl16(ga + (size_t)64 * aRS, &sm[nb][0][2048 + t * 8]);
      gl16(gb, &sm[nb][1][t * 8]);
      gl16(gb + (size_t)64 * aRS, &sm[nb][1][2048 + t * 8]);
    }
    const us* sa = sm[cur][0];
    const us* sb = sm[cur][1];
    short8 af[4], bfr[4];
#pragma unroll
    for (int i = 0; i < 4; ++i)
      af[i] = *(const short8*)&sa[(wm + i * 16 + lr) * 32 + kk];
#pragma unroll
    for (int j = 0; j < 4; ++j)
      bfr[j] = *(const short8*)&sb[(wp + j * 16 + lr) * 32 + kk];
#pragma unroll
    for (int i = 0; i < 4; ++i)
#pragma unroll
      for (int j = 0; j < 4; ++j)
        acc[i][j] = __builtin_amdgcn_mfma_f32_16x16x32_bf16(af[i], bfr[j], acc[i][j], 0, 0, 0);
    cur ^= 1;
  }

  const int rb = (lane >> 4) * 4;
#pragma unroll
  for (int j = 0; j < 4; ++j) {
    const int p = wp + j * 16 + lr;
    const float bv = bias[g * D_ + p];
    us* op = outBf + ((size_t)(b * GS_ + g) * D_ + p) * M_;
#pragma unroll
    for (int i = 0; i < 4; ++i) {
      const int n = mt * 128 + wm + i * 16 + rb;
      f32x4 v = acc[i][j];
      ushort4 o;
      o.x = f2bf(v[0] + bv); o.y = f2bf(v[1] + bv);
      o.z = f2bf(v[2] + bv); o.w = f2bf(v[3] + bv);
      *(ushort4*)(op + n) = o;
    }
  }
}

// ---- fused adjacency GEMM + relu + channel-max + residual (+ final proj) --
// grid 256, 512 thr = 8 waves = 4 channels x 2 col-halves. Block = 64 m-rows.
// 3-buffer pipeline: 1 raw s_barrier/K-step, counted vmcnt(6) (never 0 in
// steady state). Block-cooperative staging: channel g's buffer (A[64][32] +
// B[128][32], swizzled) staged by waves 2g/2g+1 (6 gl16 each).
template<int FIRST, int LAST>
__launch_bounds__(512, 2)
__global__ void k_fused(const us* __restrict__ Gh, const us* __restrict__ MhT,
                        float* __restrict__ h, us* __restrict__ hb,
                        const float* __restrict__ Wout, const float* __restrict__ bout,
                        float* __restrict__ out) {
  __shared__ __align__(16) us sm[3 * 24576];  // 3 x 48 KB = 144 KB
  const int bid = blockIdx.x;
  const int swz = (bid & 7) * 32 + (bid >> 3);   // all mt of a b on one XCD
  const int b = swz >> 3, mt = swz & 7;

  const int t = threadIdx.x;
  const int w = t >> 6;
  const int g = w >> 1;          // channel 0..3
  const int hf = w & 1;          // col half
  const int lane = t & 63;
  const int lr = lane & 15;
  const int kq = lane >> 4;

  const us* AgB = Gh + ((size_t)(b * GS_ + g) * M_ + mt * 64) * M_;
  const us* BgB = MhT + (size_t)(b * GS_ + g) * D_ * M_;
  // staging: lane l covers (local row l>>2, chunk l&3); source chunk pre-swizzled
  const int srow = lane >> 2;
  const int scol = ((lane & 3) ^ ((lane >> 3) & 3)) * 8;
  const int s0 = hf * 6;  // first of my 6 stripes (1 KB each; 0-3=A, 4-11=B)

#define STAGE(bufi, ks) do { \
    us* bb_ = sm + (bufi) * 24576 + g * 6144; \
    _Pragma("unroll") \
    for (int u_ = 0; u_ < 6; ++u_) { \
      const int ls_ = s0 + u_; \
      const us* src_ = (ls_ < 4) \
        ? AgB + (size_t)(ls_ * 16 + srow) * M_ + (ks) * 32 + scol \
        : BgB + (size_t)((ls_ - 4) * 16 + srow) * M_ + (ks) * 32 + scol; \
      gl16(src_, bb_ + ls_ * 512 + lane * 8); \
    } \
  } while (0)

  f32x4 acc[4][4];
#pragma unroll
  for (int i = 0; i < 4; ++i)
#pragma unroll
    for (int j = 0; j < 4; ++j) acc[i][j] = (f32x4){0.f, 0.f, 0.f, 0.f};

  STAGE(0, 0);
  STAGE(1, 1);

  const int kk = ((kq ^ ((lr >> 1) & 3))) * 8;  // swizzled read chunk

#pragma unroll
  for (int ks = 0; ks < 16; ++ks) {
    if (ks < 15) asm volatile("s_waitcnt vmcnt(6)" ::: "memory");
    else         asm volatile("s_waitcnt vmcnt(0)" ::: "memory");
    __builtin_amdgcn_s_barrier();
    __builtin_amdgcn_sched_barrier(0);
    const us* sa = sm + (ks % 3) * 24576 + g * 6144;
    const us* sb = sa + 2048;
    short8 af[4], bf[4];
#pragma unroll
    for (int i = 0; i < 4; ++i)
      af[i] = *(const short8*)&sa[(i * 16 + lr) * 32 + kk];
#pragma unroll
    for (int j = 0; j < 4; ++j)
      bf[j] = *(const short8*)&sb[(hf * 64 + j * 16 + lr) * 32 + kk];
    if (ks + 2 < 16) STAGE((ks + 2) % 3, ks + 2);
    asm volatile("s_waitcnt lgkmcnt(0)" ::: "memory");
    __builtin_amdgcn_sched_barrier(0);
#pragma unroll
    for (int i = 0; i < 4; ++i)
#pragma unroll
      for (int j = 0; j < 4; ++j)
        acc[i][j] = __builtin_amdgcn_mfma_f32_16x16x32_bf16(af[i], bf[j], acc[i][j], 0, 0, 0);
  }
#undef STAGE

  __builtin_amdgcn_s_barrier();  // all LDS reads done; reuse as f32 [4][64][128]
  __builtin_amdgcn_sched_barrier(0);

  {  // write my relu'd tile, swizzled (16B chunk ^= row&7)
    float* red = (float*)sm + (size_t)g * 8192;
#pragma unroll
    for (int i = 0; i < 4; ++i)
#pragma unroll
      for (int j = 0; j < 4; ++j) {
        const int col = hf * 64 + j * 16 + lr;
        const int ch = col >> 2, cw = col & 3;
#pragma unroll
        for (int cc = 0; cc < 4; ++cc) {
          const int row = i * 16 + kq * 4 + cc;
          red[row * 128 + ((ch ^ (row & 7)) << 2) + cw] = fmaxf(acc[i][j][cc], 0.f);
        }
      }
  }
  __builtin_amdgcn_s_barrier();
  __builtin_amdgcn_sched_barrier(0);

  {  // cross-channel max (+residual), then store h/hb or final projection
    const int m_l = t >> 3, pq = t & 7;
    const float* red = (const float*)sm;
    float4 vm[4];
#pragma unroll
    for (int k = 0; k < 4; ++k) {
      const int ch = pq * 4 + k;
      const float* rp = red + (size_t)m_l * 128 + ((ch ^ (m_l & 7)) << 2);
      float4 v = *(const float4*)rp;
#pragma unroll
      for (int gg = 1; gg < 4; ++gg) {
        float4 u = *(const float4*)(rp + (size_t)gg * 8192);
        v.x = fmaxf(v.x, u.x); v.y = fmaxf(v.y, u.y);
        v.z = fmaxf(v.z, u.z); v.w = fmaxf(v.w, u.w);
      }
      vm[k] = v;
    }
    const size_t ho = ((size_t)b * M_ + mt * 64 + m_l) * D_ + pq * 16;
    float4* hp = (float4*)(h + ho);
    if (!FIRST) {
#pragma unroll
      for (int k = 0; k < 4; ++k) {
        float4 hv = hp[k];
        vm[k].x += hv.x; vm[k].y += hv.y; vm[k].z += hv.z; vm[k].w += hv.w;
      }
    }
    if constexpr (!LAST) {
      ushort4* hbp = (ushort4*)(hb + ho);
#pragma unroll
      for (int k = 0; k < 4; ++k) {
        float4 v = vm[k];
        hp[k] = v;
        ushort4 o;
        o.x = f2bf(v.x); o.y = f2bf(v.y); o.z = f2bf(v.z); o.w = f2bf(v.w);
        hbp[k] = o;
      }
    } else {
      float s = 0.f;
#pragma unroll
      for (int k = 0; k < 4; ++k) {
        const float4 wv = *(const float4*)(Wout + pq * 16 + k * 4);
        s += vm[k].x * wv.x + vm[k].y * wv.y + vm[k].z * wv.z + vm[k].w * wv.w;
      }
      s += __shfl_xor(s, 1);
      s += __shfl_xor(s, 2);
      s += __shfl_xor(s, 4);
      if (pq == 0) out[(size_t)b * M_ + mt * 64 + m_l] = s + bout[0];
    }
  }
}

extern "C" void kernel_launch(void* const* d_in, const int* in_sizes, int n_in,
                              void* d_out, int out_size, void* d_ws, size_t ws_size,
                              hipStream_t stream) {
  const float* G    = (const float*)d_in[0];
  const float* x    = (const float*)d_in[1];
  const float* W0   = (const float*)d_in[2];
  const float* b0   = (const float*)d_in[3];
  const float* Wl   = (const float*)d_in[4];
  const float* bl   = (const float*)d_in[5];
  const float* Wout = (const float*)d_in[6];
  const float* bout = (const float*)d_in[7];

  char* ws = (char*)d_ws;
  us*    Gh   = (us*)(ws);
  us*    MhT  = (us*)(ws + 67108864);
  float* h    = (float*)(ws + 83886080);
  us*    hb   = (us*)(ws + 92274688);
  us*    xb   = (us*)(ws + 96468992);
  us*    W0bT = (us*)(ws + 98566144);
  us*    WlbT = (us*)(ws + 98631680);

  k_conv<<<2048, 256, 0, stream>>>((const float4*)G, (ushort4*)Gh, (B_ * GS_ * M_ * M_) / 4);
  k_conv<<<1024, 256, 0, stream>>>((const float4*)x, (ushort4*)xb, (B_ * M_ * FN_) / 4);
  k_convW<<<1920, 256, 0, stream>>>(W0, Wl, W0bT, WlbT);

  // layer 0
  k_lin<FN_ / 32><<<512, 256, 0, stream>>>(xb, W0bT, FN_, M_ * FN_, D_ * FN_, MhT, b0);
  k_fused<1, 0><<<256, 512, 0, stream>>>(Gh, MhT, h, hb, Wout, bout, (float*)d_out);

  // layers 1..6
  for (int l = 1; l < L_ - 1; ++l) {
    k_lin<D_ / 32><<<512, 256, 0, stream>>>(hb, WlbT + (size_t)(l - 1) * GS_ * D_ * D_,
        D_, M_ * D_, D_ * D_, MhT, bl + (size_t)(l - 1) * GS_ * D_);
    k_fused<0, 0><<<256, 512, 0, stream>>>(Gh, MhT, h, hb, Wout, bout, (float*)d_out);
  }

  // layer 7: fold final projection into the fused epilogue
  k_lin<D_ / 32><<<512, 256, 0, stream>>>(hb, WlbT + (size_t)(L_ - 2) * GS_ * D_ * D_,
      D_, M_ * D_, D_ * D_, MhT, bl + (size_t)(L_ - 2) * GS_ * D_);
  k_fused<0, 1><<<256, 512, 0, stream>>>(Gh, MhT, h, hb, Wout, bout, (float*)d_out);
}